// Round 6
// baseline (312.155 us; speedup 1.0000x reference)
//
#include <hip/hip_runtime.h>

// Problem constants (fixed by setup_inputs): B=128, C=3, N=320
constexpr int B    = 128;
constexpr int C    = 3;
constexpr int N    = 320;
constexpr int G    = N * N;        // 102400 elements per (b, c) plane
constexpr int G4   = G / 4;        // 25600 float4 chunks per plane
constexpr int ROW4 = N / 4;        // 80 float4 chunks per row
constexpr int BLOCKS  = 1600;      // 1600*256 = 409600 = 16 * G4 -> q invariant per thread
constexpr int THREADS = 256;
constexpr int BSTEP   = (BLOCKS * THREADS) / G4;  // 16 batches covered per sweep
constexpr int ITERS   = B / BSTEP;                // 8 iterations, exact
constexpr unsigned long long TOTAL_EDGES =
    (unsigned long long)B * (unsigned long long)(N * (N - 1) / 2); // 6,533,120

// ws layout: ws[0] = ticket (zeroed by 4-byte memset node, own 128B line);
//            ws + 32 uints (128 B) = partials[BLOCKS] (plain stores, no init).
__global__ __launch_bounds__(THREADS, 4) void edge_acc_kernel(
    const float* __restrict__ inp,      // [B, C, G] float32
    const int*   __restrict__ tgt,      // [B, G] int32
    unsigned int* __restrict__ ws,
    float* __restrict__ out)
{
    unsigned int* ticket   = ws;
    unsigned int* partials = ws + 32;

    const int tid = blockIdx.x * THREADS + threadIdx.x;   // 0 .. 409599
    const int q   = tid % G4;            // chunk within a plane (loop-invariant)
    const int b0  = tid / G4;            // 0 .. 15
    const int i   = q / ROW4;            // row in N x N
    const int jb  = (q - i * ROW4) * 4;  // first column of this chunk

    unsigned int cnt = 0;

    // Strict upper triangle: j > i. Whole-chunk skip decided ONCE per thread.
    if (jb + 3 > i) {
        const unsigned m0 = (unsigned)(jb + 0 > i);
        const unsigned m1 = (unsigned)(jb + 1 > i);
        const unsigned m2 = (unsigned)(jb + 2 > i);
        const size_t gofs  = (size_t)q * 4;
        const float* pbase = inp + gofs;
        const int*   tbase = tgt + gofs;

        // 2-deep software pipeline (verified-correct R5 body).
        float4 x0 = *(const float4*)(pbase + (size_t)b0 * (C * G));
        float4 x1 = *(const float4*)(pbase + (size_t)b0 * (C * G) + G);
        float4 x2 = *(const float4*)(pbase + (size_t)b0 * (C * G) + 2 * G);
        int4   tv = *(const int4*)(tbase + (size_t)b0 * G);

        #pragma unroll
        for (int it = 0; it < ITERS; ++it) {
            float4 n0, n1, n2; int4 ntv;
            if (it + 1 < ITERS) {
                const int b = b0 + BSTEP * (it + 1);
                const float* p = pbase + (size_t)b * (C * G);
                n0  = *(const float4*)(p);
                n1  = *(const float4*)(p + G);
                n2  = *(const float4*)(p + 2 * G);
                ntv = *(const int4*)(tbase + (size_t)b * G);
            }

            // first-occurrence argmax over C=3 (matches jnp.argmax ties)
            {
                int pred = 0; float m = x0.x;
                if (x1.x > m) { m = x1.x; pred = 1; }
                if (x2.x > m) { pred = 2; }
                cnt += m0 & (unsigned)(pred == tv.x);
            }
            {
                int pred = 0; float m = x0.y;
                if (x1.y > m) { m = x1.y; pred = 1; }
                if (x2.y > m) { pred = 2; }
                cnt += m1 & (unsigned)(pred == tv.y);
            }
            {
                int pred = 0; float m = x0.z;
                if (x1.z > m) { m = x1.z; pred = 1; }
                if (x2.z > m) { pred = 2; }
                cnt += m2 & (unsigned)(pred == tv.z);
            }
            {
                int pred = 0; float m = x0.w;
                if (x1.w > m) { m = x1.w; pred = 1; }
                if (x2.w > m) { pred = 2; }
                cnt += (unsigned)(pred == tv.w);   // jb+3 > i guaranteed here
            }

            if (it + 1 < ITERS) { x0 = n0; x1 = n1; x2 = n2; tv = ntv; }
        }
    }

    // ---- wave shuffle -> LDS -> per-block partial + single ticket atomic ----
    #pragma unroll
    for (int off = 32; off > 0; off >>= 1)
        cnt += __shfl_down(cnt, off, 64);

    __shared__ unsigned int wsum[THREADS / 64];
    __shared__ unsigned int is_last;
    const int lane = threadIdx.x & 63;
    const int wave = threadIdx.x >> 6;
    if (lane == 0) wsum[wave] = cnt;
    __syncthreads();

    if (threadIdx.x == 0) {
        const unsigned int bsum = wsum[0] + wsum[1] + wsum[2] + wsum[3];
        partials[blockIdx.x] = bsum;          // plain store, write-through to L2
        __threadfence();                      // release: drain own store before ticket
        is_last = (atomicAdd(ticket, 1u) == (unsigned)(BLOCKS - 1));
    }
    __syncthreads();                          // broadcasts is_last; orders wsum reuse

    if (is_last) {
        // Last-arriving block: all 1599 other tickets were preceded by a
        // fence after their partial store -> totals are in L2. Acquire:
        __threadfence();                      // invalidate L1 before reading partials
        unsigned int s = 0;
        for (int idx = threadIdx.x; idx < BLOCKS; idx += THREADS)
            s += partials[idx];

        #pragma unroll
        for (int off = 32; off > 0; off >>= 1)
            s += __shfl_down(s, off, 64);

        if (lane == 0) wsum[wave] = s;
        __syncthreads();                      // block-uniform branch: safe

        if (threadIdx.x == 0) {
            const unsigned int total = wsum[0] + wsum[1] + wsum[2] + wsum[3];
            out[0] = 1.0f - (float)((double)total / (double)TOTAL_EDGES);
        }
    }
}

extern "C" void kernel_launch(void* const* d_in, const int* in_sizes, int n_in,
                              void* d_out, int out_size, void* d_ws, size_t ws_size,
                              hipStream_t stream) {
    const float* inp = (const float*)d_in[0];
    const int*   tgt = (const int*)d_in[1];
    float*       out = (float*)d_out;
    unsigned int* ws = (unsigned int*)d_ws;

    // Zero ONLY the ticket word (d_ws is 0xAA-poisoned before every launch).
    hipMemsetAsync(ws, 0, sizeof(unsigned int), stream);
    edge_acc_kernel<<<BLOCKS, THREADS, 0, stream>>>(inp, tgt, ws, out);
}

// Round 7
// 235.574 us; speedup vs baseline: 1.3251x; 1.3251x over previous
//
#include <hip/hip_runtime.h>

// Problem constants (fixed by setup_inputs): B=128, C=3, N=320
constexpr int B    = 128;
constexpr int C    = 3;
constexpr int N    = 320;
constexpr int G    = N * N;        // 102400 elements per (b, c) plane
constexpr int G4   = G / 4;        // 25600 float4 chunks per plane
constexpr int ROW4 = N / 4;        // 80 float4 chunks per row
constexpr int BLOCKS  = 3200;      // 3200*256 = 819200 = 32 * G4 -> q invariant per thread
constexpr int THREADS = 256;
constexpr int BSTEP   = (BLOCKS * THREADS) / G4;  // 32 batches covered per sweep
constexpr int ITERS   = B / BSTEP;                // 4 iterations, exact
constexpr unsigned long long TOTAL_EDGES =
    (unsigned long long)B * (unsigned long long)(N * (N - 1) / 2); // 6,533,120

// R6 lesson: NO __threadfence() tail (device-scope fence ~ L2 writeback on
// gfx950, +78 us for 1600 blocks). Two-kernel structure, plain stores.
// R4/R6 lesson: VGPR=32 serializes loads. Structure below forces the
// allocator to keep ALL 16 loads in flight: load phase fully unrolled,
// compute phase consumes in REVERSE load order (first consumption waits on
// the LAST issued load -> no load can be sunk below any consumption).
__global__ __launch_bounds__(THREADS, 4) void edge_acc_kernel(
    const float* __restrict__ inp,      // [B, C, G] float32
    const int*   __restrict__ tgt,      // [B, G] int32
    unsigned int* __restrict__ partials) // [BLOCKS], plain stores (no init needed)
{
    const int tid = blockIdx.x * THREADS + threadIdx.x;   // 0 .. 819199
    const int q   = tid % G4;            // chunk within a plane (loop-invariant)
    const int b0  = tid / G4;            // 0 .. 31
    const int i   = q / ROW4;            // row in N x N
    const int jb  = (q - i * ROW4) * 4;  // first column of this chunk

    unsigned int cnt = 0;

    if (jb + 3 > i) {                    // strict upper triangle: whole-chunk test
        const unsigned m0 = (unsigned)(jb + 0 > i);
        const unsigned m1 = (unsigned)(jb + 1 > i);
        const unsigned m2 = (unsigned)(jb + 2 > i);
        const size_t gofs  = (size_t)q * 4;
        const float* pbase = inp + gofs;
        const int*   tbase = tgt + gofs;

        float4 X0[ITERS], X1[ITERS], X2[ITERS];
        int4   TV[ITERS];

        // ---- phase 1: issue ALL 16 vector loads (64 result dwords) ----
        #pragma unroll
        for (int it = 0; it < ITERS; ++it) {
            const int b = b0 + BSTEP * it;
            const float* p = pbase + (size_t)b * (C * G);
            X0[it] = *(const float4*)(p);
            X1[it] = *(const float4*)(p + G);
            X2[it] = *(const float4*)(p + 2 * G);
            TV[it] = *(const int4*)(tbase + (size_t)b * G);
        }

        // ---- phase 2: consume in REVERSE order (pins all loads above) ----
        #pragma unroll
        for (int r = ITERS - 1; r >= 0; --r) {
            const float4 x0 = X0[r], x1 = X1[r], x2 = X2[r];
            const int4   tv = TV[r];
            // first-occurrence argmax over C=3 (matches jnp.argmax ties)
            {
                int pred = 0; float m = x0.x;
                if (x1.x > m) { m = x1.x; pred = 1; }
                if (x2.x > m) { pred = 2; }
                cnt += m0 & (unsigned)(pred == tv.x);
            }
            {
                int pred = 0; float m = x0.y;
                if (x1.y > m) { m = x1.y; pred = 1; }
                if (x2.y > m) { pred = 2; }
                cnt += m1 & (unsigned)(pred == tv.y);
            }
            {
                int pred = 0; float m = x0.z;
                if (x1.z > m) { m = x1.z; pred = 1; }
                if (x2.z > m) { pred = 2; }
                cnt += m2 & (unsigned)(pred == tv.z);
            }
            {
                int pred = 0; float m = x0.w;
                if (x1.w > m) { m = x1.w; pred = 1; }
                if (x2.w > m) { pred = 2; }
                cnt += (unsigned)(pred == tv.w);   // jb+3 > i guaranteed here
            }
        }
    }

    // ---- wave (64-lane shuffle) -> block (LDS) -> one plain store per block ----
    #pragma unroll
    for (int off = 32; off > 0; off >>= 1)
        cnt += __shfl_down(cnt, off, 64);

    __shared__ unsigned int wsum[THREADS / 64];
    const int lane = threadIdx.x & 63;
    const int wave = threadIdx.x >> 6;
    if (lane == 0) wsum[wave] = cnt;
    __syncthreads();

    if (threadIdx.x == 0)
        partials[blockIdx.x] = wsum[0] + wsum[1] + wsum[2] + wsum[3];
}

// Single-wave finalize: no LDS, no __syncthreads, uint4 partial reads.
__global__ __launch_bounds__(64) void finalize_kernel(
    const unsigned int* __restrict__ partials,  // [BLOCKS], BLOCKS % 4 == 0
    float* __restrict__ out)
{
    unsigned int s = 0;
    const uint4* p4 = (const uint4*)partials;
    for (int idx = threadIdx.x; idx < BLOCKS / 4; idx += 64) {
        const uint4 v = p4[idx];
        s += v.x + v.y + v.z + v.w;
    }

    #pragma unroll
    for (int off = 32; off > 0; off >>= 1)
        s += __shfl_down(s, off, 64);

    if (threadIdx.x == 0)
        out[0] = 1.0f - (float)((double)s / (double)TOTAL_EDGES);
}

extern "C" void kernel_launch(void* const* d_in, const int* in_sizes, int n_in,
                              void* d_out, int out_size, void* d_ws, size_t ws_size,
                              hipStream_t stream) {
    const float* inp = (const float*)d_in[0];
    const int*   tgt = (const int*)d_in[1];
    float*       out = (float*)d_out;
    unsigned int* partials = (unsigned int*)d_ws;  // BLOCKS * 4 bytes used

    edge_acc_kernel<<<BLOCKS, THREADS, 0, stream>>>(inp, tgt, partials);
    finalize_kernel<<<1, 64, 0, stream>>>(partials, out);
}

// Round 8
// 234.873 us; speedup vs baseline: 1.3290x; 1.0030x over previous
//
#include <hip/hip_runtime.h>

// Problem constants (fixed by setup_inputs): B=128, C=3, N=320
constexpr int B    = 128;
constexpr int C    = 3;
constexpr int N    = 320;
constexpr int G    = N * N;        // 102400 elements per (b, c) plane
constexpr int G4   = G / 4;        // 25600 float4 chunks per plane
constexpr int ROW4 = N / 4;        // 80 float4 chunks per row
constexpr int BLOCKS  = 3200;      // 3200*256 = 819200 = 32 * G4 -> q invariant per thread
constexpr int THREADS = 256;
constexpr int BSTEP   = (BLOCKS * THREADS) / G4;  // 32 batches covered per sweep
constexpr int ITERS   = B / BSTEP;                // 4 iterations, exact
constexpr unsigned long long TOTAL_EDGES =
    (unsigned long long)B * (unsigned long long)(N * (N - 1) / 2); // 6,533,120

// R6 evidence: compiler flattens any source-level pipeline (VGPR stayed 32 ->
// loads serialized at ~3 outstanding/CU -> body latency-bound at ~47 us).
// Fix: issue ALL 16 loads, then an asm memory fence. Loads cannot sink past a
// may-write-memory barrier, so 64 result dwords are forced live in VGPRs and
// all 16 loads stay in flight. Consume in FORWARD issue order: vmcnt drains
// in issue order -> staged waitcnt vmcnt(12/8/4/0), overlapping tail latency.
__global__ __launch_bounds__(THREADS, 4) void edge_acc_kernel(
    const float* __restrict__ inp,      // [B, C, G] float32
    const int*   __restrict__ tgt,      // [B, G] int32
    unsigned int* __restrict__ partials) // [BLOCKS], plain stores (no init needed)
{
    const int tid = blockIdx.x * THREADS + threadIdx.x;   // 0 .. 819199
    const int q   = tid % G4;            // chunk within a plane (loop-invariant)
    const int b0  = tid / G4;            // 0 .. 31
    const int i   = q / ROW4;            // row in N x N
    const int jb  = (q - i * ROW4) * 4;  // first column of this chunk

    unsigned int cnt = 0;

    if (jb + 3 > i) {                    // strict upper triangle: whole-chunk test
        const unsigned m0 = (unsigned)(jb + 0 > i);
        const unsigned m1 = (unsigned)(jb + 1 > i);
        const unsigned m2 = (unsigned)(jb + 2 > i);
        const size_t gofs  = (size_t)q * 4;
        const float* pbase = inp + gofs;
        const int*   tbase = tgt + gofs;

        float4 X0[ITERS], X1[ITERS], X2[ITERS];
        int4   TV[ITERS];

        // ---- phase 1: issue ALL 16 vector loads (64 result dwords) ----
        #pragma unroll
        for (int it = 0; it < ITERS; ++it) {
            const int b = b0 + BSTEP * it;
            const float* p = pbase + (size_t)b * (C * G);
            X0[it] = *(const float4*)(p);
            X1[it] = *(const float4*)(p + G);
            X2[it] = *(const float4*)(p + 2 * G);
            TV[it] = *(const int4*)(tbase + (size_t)b * G);
        }

        // Compiler-level fence: loads above cannot sink below this point
        // (they read memory the asm may write). Forces all 16 in flight.
        asm volatile("" ::: "memory");

        // ---- phase 2: consume in FORWARD issue order (staged vmcnt) ----
        #pragma unroll
        for (int it = 0; it < ITERS; ++it) {
            const float4 x0 = X0[it], x1 = X1[it], x2 = X2[it];
            const int4   tv = TV[it];
            // first-occurrence argmax over C=3 (matches jnp.argmax ties)
            {
                int pred = 0; float m = x0.x;
                if (x1.x > m) { m = x1.x; pred = 1; }
                if (x2.x > m) { pred = 2; }
                cnt += m0 & (unsigned)(pred == tv.x);
            }
            {
                int pred = 0; float m = x0.y;
                if (x1.y > m) { m = x1.y; pred = 1; }
                if (x2.y > m) { pred = 2; }
                cnt += m1 & (unsigned)(pred == tv.y);
            }
            {
                int pred = 0; float m = x0.z;
                if (x1.z > m) { m = x1.z; pred = 1; }
                if (x2.z > m) { pred = 2; }
                cnt += m2 & (unsigned)(pred == tv.z);
            }
            {
                int pred = 0; float m = x0.w;
                if (x1.w > m) { m = x1.w; pred = 1; }
                if (x2.w > m) { pred = 2; }
                cnt += (unsigned)(pred == tv.w);   // jb+3 > i guaranteed here
            }
        }
    }

    // ---- wave (64-lane shuffle) -> block (LDS) -> one plain store per block ----
    #pragma unroll
    for (int off = 32; off > 0; off >>= 1)
        cnt += __shfl_down(cnt, off, 64);

    __shared__ unsigned int wsum[THREADS / 64];
    const int lane = threadIdx.x & 63;
    const int wave = threadIdx.x >> 6;
    if (lane == 0) wsum[wave] = cnt;
    __syncthreads();

    if (threadIdx.x == 0)
        partials[blockIdx.x] = wsum[0] + wsum[1] + wsum[2] + wsum[3];
}

// Single-wave finalize: no LDS, no __syncthreads, uint4 partial reads.
__global__ __launch_bounds__(64) void finalize_kernel(
    const unsigned int* __restrict__ partials,  // [BLOCKS], BLOCKS % 4 == 0
    float* __restrict__ out)
{
    unsigned int s = 0;
    const uint4* p4 = (const uint4*)partials;
    for (int idx = threadIdx.x; idx < BLOCKS / 4; idx += 64) {
        const uint4 v = p4[idx];
        s += v.x + v.y + v.z + v.w;
    }

    #pragma unroll
    for (int off = 32; off > 0; off >>= 1)
        s += __shfl_down(s, off, 64);

    if (threadIdx.x == 0)
        out[0] = 1.0f - (float)((double)s / (double)TOTAL_EDGES);
}

extern "C" void kernel_launch(void* const* d_in, const int* in_sizes, int n_in,
                              void* d_out, int out_size, void* d_ws, size_t ws_size,
                              hipStream_t stream) {
    const float* inp = (const float*)d_in[0];
    const int*   tgt = (const int*)d_in[1];
    float*       out = (float*)d_out;
    unsigned int* partials = (unsigned int*)d_ws;  // BLOCKS * 4 bytes used

    edge_acc_kernel<<<BLOCKS, THREADS, 0, stream>>>(inp, tgt, partials);
    finalize_kernel<<<1, 64, 0, stream>>>(partials, out);
}